// Round 5
// baseline (346.680 us; speedup 1.0000x reference)
//
#include <hip/hip_runtime.h>
#include <hip/hip_bf16.h>

typedef __bf16 bf16_t;
typedef bf16_t bf16x8 __attribute__((ext_vector_type(8)));
typedef bf16_t bf16x4 __attribute__((ext_vector_type(4)));
typedef bf16_t bf16x2 __attribute__((ext_vector_type(2)));
typedef float f32x4 __attribute__((ext_vector_type(4)));

#define B_   4
#define S_   1024
#define H_   32
#define KVH_ 8
#define D_   128
#define WIN_ 512
#define KVD_ (KVH_ * D_)                 // 1024
#define LOG2E_ 1.4426950408889634f
// log2-domain softcap: capL = 50*log2e*tanh(score*scale/50)
// Softcap BOUNDS the logits (|capL| <= K2_), so softmax uses a FIXED max:
//   p = exp2(capL - K2_) = exp2(-2*K2_ / (ez+1)),  ez = exp2(score*C1_)
#define C1_ (2.0f * (0.08838834764831845f / 50.0f) * LOG2E_)
#define K2_ (50.0f * LOG2E_)
#define NK22_ (-2.0f * K2_)
#define EXP2F_(x) __builtin_amdgcn_exp2f(x)

// ---------------- fused attention, 4 fat waves -----------------------------
// wg = (b, kvh, 32-row q-tile), 256 thr = 4 waves; wave = 1 head x 32 q-rows
// (2 B-operand col-blocks).  Halves the dominant LDS read traffic vs the
// 8-wave layout: each K/V A/B-fragment read feeds 2 MFMAs (qb=0,1) instead
// of 1.  Per wg-tile LDS ~96KB (was 160KB).  KVBLK=32, LDS 40KB.
// Staging: waves 0-1 stage K (128B/thread fp32, coalesced, b128 swizzled
// stores ^(row&15)); waves 2-3 stage V (2 tokens x 16 d per thread; the
// phase now mixes two token-pairs -> V^T 4B stores are 2-way = free).
// Reg-staged double buffer, loads at tile top, writes after compute, ONE
// barrier per tile.  Fixed-max softmax; no online rescale.
__global__ __launch_bounds__(256, 3) void attn_fwd(
    const float* __restrict__ Q, const float* __restrict__ K,
    const float* __restrict__ V, float* __restrict__ Out)
{
  // XCD-aware bijective swizzle: each XCD gets 4 whole (b,kvh) heads.
  const int fid = blockIdx.x + 32 * (blockIdx.y + 8 * (int)blockIdx.z);
  const int swz = (fid & 7) * 128 + (fid >> 3);
  const int i0  = (swz & 31) * 32;
  const int kvh = (swz >> 5) & 7;
  const int b   = swz >> 8;

  const int tid  = threadIdx.x;
  const int w    = tid >> 6;               // 0..3 = head g
  const int lane = tid & 63;
  const int m16  = lane & 15;
  const int quad = lane >> 4;
  const int h    = kvh * 4 + w;
  const int sw16 = (m16 >> 1) & 3;

  __shared__ __align__(16) bf16_t KsB[2][32 * 128];  // 8KB x2
  __shared__ __align__(16) bf16_t VtB[2][128 * 32];  // 8KB x2 (V^T)
  __shared__ __align__(16) bf16_t PsB[4 * 32 * 32];  // 8KB (32q x 32k / wave)

  // Q fragments (B-operand): qf[qb][s], rows i0+qb*16+m16, d = 32s+8quad
  bf16x8 qf[2][4];
  #pragma unroll
  for (int qb = 0; qb < 2; ++qb) {
    const float* qp = Q + ((size_t)(b * S_ + i0 + qb * 16 + m16) * H_ + h) * D_;
    #pragma unroll
    for (int s = 0; s < 4; ++s) {
      const int d0 = 32 * s + 8 * quad;
      float4 f0 = *(const float4*)(qp + d0);
      float4 f1 = *(const float4*)(qp + d0 + 4);
      bf16x8 t = { (bf16_t)f0.x, (bf16_t)f0.y, (bf16_t)f0.z, (bf16_t)f0.w,
                   (bf16_t)f1.x, (bf16_t)f1.y, (bf16_t)f1.z, (bf16_t)f1.w };
      qf[qb][s] = t;
    }
  }

  f32x4 O[2][8];
  #pragma unroll
  for (int qb = 0; qb < 2; ++qb)
    #pragma unroll
    for (int c = 0; c < 8; ++c) O[qb][c] = (f32x4){0.f, 0.f, 0.f, 0.f};
  f32x4 lacc[2] = { (f32x4){0.f,0.f,0.f,0.f}, (f32x4){0.f,0.f,0.f,0.f} };

  // ---- staging geometry (wave-uniform role split: waves 0-1 K, 2-3 V) ----
  const bool isK = (w < 2);
  const int kt   = tid & 127;
  const int krow = kt >> 2;                // 0..31
  const int kc0  = (kt & 3) * 4;           // chunks kc0..kc0+3 (8 bf16 each)
  const float* kbase = K + ((size_t)(b * S_ + krow) * KVH_ + kvh) * D_ + kc0 * 8;
  const int vtt  = tid & 127;
  const int tv   = (vtt >> 3) * 2;         // token pair 0,2,..,30
  const int mgrp = vtt & 7;                // d-group: d0 = mgrp*16
  const int d0v  = mgrp * 16;
  const float* vbase = V + ((size_t)(b * S_ + tv) * KVH_ + kvh) * D_ + d0v;

  const int t_lo = (i0 >= WIN_) ? ((i0 - (WIN_ - 1)) >> 5) : 0;
  const int t_hi = i0 >> 5;

  float4 sr[8];
  auto stage_load = [&](int j0n) {
    if (isK) {
      const float* p = kbase + (size_t)j0n * KVD_;   // 128B contiguous
      #pragma unroll
      for (int c = 0; c < 8; ++c) sr[c] = *(const float4*)(p + c * 4);
    } else {
      const float* p = vbase + (size_t)j0n * KVD_;
      #pragma unroll
      for (int c = 0; c < 4; ++c) sr[c]     = *(const float4*)(p + c * 4);
      #pragma unroll
      for (int c = 0; c < 4; ++c) sr[4 + c] = *(const float4*)(p + KVD_ + c * 4);
    }
  };
  auto stage_write_K = [&](int bi) {
    #pragma unroll
    for (int cc = 0; cc < 4; ++cc) {
      const int ch = kc0 + cc;
      float4 a = sr[2 * cc], bq = sr[2 * cc + 1];
      bf16x8 o = { (bf16_t)a.x, (bf16_t)a.y, (bf16_t)a.z, (bf16_t)a.w,
                   (bf16_t)bq.x, (bf16_t)bq.y, (bf16_t)bq.z, (bf16_t)bq.w };
      *(bf16x8*)&KsB[bi][krow * 128 + ((ch ^ (krow & 15)) << 3)] = o;
    }
  };
  auto stage_write_V = [&](int bi) {
    #pragma unroll
    for (int e = 0; e < 16; ++e) {
      const int d   = d0v + e;
      const int mpr = d >> 3, e7 = d & 7;
      const float va = ((const float*)&sr[e >> 2])[e & 3];          // tok tv
      const float vb = ((const float*)&sr[4 + (e >> 2)])[e & 3];    // tok tv+1
      bf16x2 pr = { (bf16_t)va, (bf16_t)vb };
      const int addr = mpr * 256 + e7 * 32 +
                       ((((tv >> 3) ^ ((mpr >> 1) & 3) ^ (e7 >> 1))) << 3) +
                       (tv & 7);
      *(bf16x2*)&VtB[bi][addr] = pr;
    }
  };

  // prologue: stage tile t_lo into buffer 0
  stage_load(t_lo * 32);
  if (isK) stage_write_K(0); else stage_write_V(0);
  __syncthreads();
  int buf = 0;

  const int pw = w * (32 * 32);

  for (int tb = t_lo; tb <= t_hi; ++tb) {
    const int j0  = tb * 32;
    const bool pre = (tb < t_hi);
    if (pre) stage_load(j0 + 32);   // issue-early; hides under compute

    // ---- S^T = K·Q^T (A-frag shared across qb) ----
    f32x4 acc[2][2];
    #pragma unroll
    for (int kb = 0; kb < 2; ++kb)
      #pragma unroll
      for (int qb = 0; qb < 2; ++qb) acc[kb][qb] = (f32x4){0.f,0.f,0.f,0.f};
    __builtin_amdgcn_s_setprio(1);
    #pragma unroll
    for (int kb = 0; kb < 2; ++kb) {
      const int row = 16 * kb + m16;
      #pragma unroll
      for (int s = 0; s < 4; ++s) {
        bf16x8 a = *(const bf16x8*)&KsB[buf][row * 128 + (((quad + 4 * s) ^ m16) << 3)];
        acc[kb][0] = __builtin_amdgcn_mfma_f32_16x16x32_bf16(a, qf[0][s], acc[kb][0], 0, 0, 0);
        acc[kb][1] = __builtin_amdgcn_mfma_f32_16x16x32_bf16(a, qf[1][s], acc[kb][1], 0, 0, 0);
      }
    }
    __builtin_amdgcn_s_setprio(0);

    // ---- softcap -> p (fixed max) -> P to LDS ----
    #pragma unroll
    for (int kb = 0; kb < 2; ++kb)
      #pragma unroll
      for (int qb = 0; qb < 2; ++qb) {
        const int iwq = i0 + qb * 16;
        const bool fullb = (j0 + 16 * kb + 15 <= iwq) &&
                           (iwq + 15 - (j0 + 16 * kb) < WIN_);
        bf16x4 pk;
        #pragma unroll
        for (int r = 0; r < 4; ++r) {
          float ez = EXP2F_(acc[kb][qb][r] * C1_);
          float p  = EXP2F_(NK22_ * __builtin_amdgcn_rcpf(ez + 1.f));
          if (!fullb) {
            const int j = j0 + 16 * kb + 4 * quad + r;
            const int i = iwq + m16;
            p = ((j <= i) && (i - j < WIN_)) ? p : 0.f;
          }
          lacc[qb][r] += p;
          pk[r] = (bf16_t)p;
        }
        const int ch = (2 * kb + (quad >> 1)) ^ sw16;
        *(bf16x4*)&PsB[pw + (qb * 16 + m16) * 32 + ch * 8 + (quad & 1) * 4] = pk;
      }

    if (pre && isK) stage_write_K(buf ^ 1);   // buf^1 idle: no barrier needed

    // ---- O += P·V (V B-frag shared across qb) ----
    bf16x8 pa0 = *(const bf16x8*)&PsB[pw + (m16)      * 32 + ((quad ^ sw16) << 3)];
    bf16x8 pa1 = *(const bf16x8*)&PsB[pw + (16 + m16) * 32 + ((quad ^ sw16) << 3)];
    __builtin_amdgcn_s_setprio(1);
    #pragma unroll
    for (int c = 0; c < 8; ++c) {
      const int vrow = 16 * c + m16;
      bf16x8 v = *(const bf16x8*)&VtB[buf][vrow * 32 + (((quad ^ sw16) ^ (c & 3)) << 3)];
      O[0][c] = __builtin_amdgcn_mfma_f32_16x16x32_bf16(pa0, v, O[0][c], 0, 0, 0);
      O[1][c] = __builtin_amdgcn_mfma_f32_16x16x32_bf16(pa1, v, O[1][c], 0, 0, 0);
    }
    __builtin_amdgcn_s_setprio(0);

    if (pre && !isK) stage_write_V(buf ^ 1);
    __syncthreads();
    buf ^= 1;
  }

  // ---- epilogue ----
  #pragma unroll
  for (int qb = 0; qb < 2; ++qb) {
    float l = lacc[qb][0] + lacc[qb][1] + lacc[qb][2] + lacc[qb][3];
    l += __shfl_xor(l, 16);
    l += __shfl_xor(l, 32);
    #pragma unroll
    for (int r = 0; r < 4; ++r) {
      const int rr = 4 * quad + r;
      const float lr = __shfl(l, rr);
      const float linv = __builtin_amdgcn_rcpf(lr);
      float* po = Out + ((size_t)(b * S_ + i0 + qb * 16 + rr) * H_ + h) * D_;
      #pragma unroll
      for (int c = 0; c < 8; ++c) po[c * 16 + m16] = O[qb][c][r] * linv;
    }
  }
}

extern "C" void kernel_launch(void* const* d_in, const int* in_sizes, int n_in,
                              void* d_out, int out_size, void* d_ws, size_t ws_size,
                              hipStream_t stream) {
  const float* q = (const float*)d_in[0];
  const float* k = (const float*)d_in[1];
  const float* v = (const float*)d_in[2];
  float* out = (float*)d_out;
  // Single fused kernel: no prepass, no workspace, no input mutation.
  attn_fwd<<<dim3(S_ / 32, KVH_, B_), 256, 0, stream>>>(q, k, v, out);
}

// Round 6
// 209.867 us; speedup vs baseline: 1.6519x; 1.6519x over previous
//
#include <hip/hip_runtime.h>
#include <hip/hip_bf16.h>

typedef __bf16 bf16_t;
typedef bf16_t bf16x8 __attribute__((ext_vector_type(8)));
typedef bf16_t bf16x4 __attribute__((ext_vector_type(4)));
typedef bf16_t bf16x2 __attribute__((ext_vector_type(2)));
typedef float f32x4 __attribute__((ext_vector_type(4)));

#define B_   4
#define S_   1024
#define H_   32
#define KVH_ 8
#define D_   128
#define WIN_ 512
#define KVD_ (KVH_ * D_)                 // 1024
#define LOG2E_ 1.4426950408889634f
// log2-domain softcap: capL = 50*log2e*tanh(score*scale/50)
// Softcap BOUNDS the logits (|capL| <= K2_), so softmax uses a FIXED max:
//   p = exp2(capL - K2_) = exp2(-2*K2_ / (ez+1)),  ez = exp2(score*C1_)
// Exact (same p/l ratios); kills all online-max machinery.
#define C1_ (2.0f * (0.08838834764831845f / 50.0f) * LOG2E_)
#define K2_ (50.0f * LOG2E_)
#define NK22_ (-2.0f * K2_)
#define EXP2F_(x) __builtin_amdgcn_exp2f(x)

// ---------------- fused attention (single kernel, fp32-direct) -------------
// wg = (b, kvh, 32-row q-tile), 512 thr = 8 waves = 4 heads x 2 row-blocks.
// Round-3 structure (91.4us verified; VGPR 64, no spill) + 2 fixes:
//  (1) LPT dispatch: i0 = (31 - (swz&31))*32.  Work/wg = qb+1..17 tiles;
//      ascending-qb order ran SHORTEST-FIRST, leaving a sparse tail of
//      17-tile wgs (Occupancy 31%).  Longest-first packs the tail.
//  (2) V-staging lane remap: old mapping gave each 16-lane issue phase one
//      token-pair and 16 mpr values -> 4 lanes per bank-slot (4-way, 4.18M
//      conflict cycles).  New bit split (mpr = b0-2|b4, tv = b3|b5-7) mixes
//      two token-pairs (+-4B bank offset) x 8 mpr (2 lanes/slot) -> 2-way
//      = free.  LDS layout function f(d) unchanged; PV read side untouched.
__global__ __launch_bounds__(512, 4) void attn_fwd(
    const float* __restrict__ Q, const float* __restrict__ K,
    const float* __restrict__ V, float* __restrict__ Out)
{
  // XCD-aware bijective swizzle: each XCD gets 4 whole (b,kvh) heads.
  const int fid = blockIdx.x + 32 * (blockIdx.y + 8 * (int)blockIdx.z);
  const int swz = (fid & 7) * 128 + (fid >> 3);
  const int i0  = (31 - (swz & 31)) * 32;   // LPT: longest wgs first
  const int kvh = (swz >> 5) & 7;
  const int b   = swz >> 8;

  const int tid  = threadIdx.x;
  const int w    = tid >> 6;
  const int lane = tid & 63;
  const int m16  = lane & 15;
  const int quad = lane >> 4;
  const int g    = w & 3;
  const int rb   = w >> 2;
  const int h    = kvh * 4 + g;
  const int iw   = i0 + rb * 16;
  const int i    = iw + m16;
  const int sw16 = (m16 >> 1) & 3;        // 32-wide-row swizzle key (low part)

  __shared__ __align__(16) bf16_t KsB[2][32 * 128];  // 8KB x2
  __shared__ __align__(16) bf16_t VtB[2][128 * 32];  // 8KB x2 (V^T)
  __shared__ __align__(16) bf16_t PsB[8 * 16 * 32];  // 8KB

  // Q fragments (B-operand layout)
  bf16x8 qf[4];
  {
    const float* qp = Q + ((size_t)(b * S_ + iw + m16) * H_ + h) * D_;
    #pragma unroll
    for (int s = 0; s < 4; ++s) {
      const int d0 = 32 * s + 8 * quad;
      float4 f0 = *(const float4*)(qp + d0);
      float4 f1 = *(const float4*)(qp + d0 + 4);
      bf16x8 t = { (bf16_t)f0.x, (bf16_t)f0.y, (bf16_t)f0.z, (bf16_t)f0.w,
                   (bf16_t)f1.x, (bf16_t)f1.y, (bf16_t)f1.z, (bf16_t)f1.w };
      qf[s] = t;
    }
  }

  f32x4 O[8];
  #pragma unroll
  for (int c = 0; c < 8; ++c) O[c] = (f32x4){0.f, 0.f, 0.f, 0.f};
  f32x4 lacc = (f32x4){0.f, 0.f, 0.f, 0.f};

  // ---- staging geometry (wave-uniform role split) ----
  const bool isK = (tid < 256);
  // K role: 256 thr, each 1 token row x 16 floats (64B contiguous)
  const int krow = tid >> 3;               // 0..31
  const int kseg = tid & 7;                // 16-float segment
  const float* ksrc = K + ((size_t)(b * S_ + krow) * KVH_ + kvh) * D_ + kseg * 16;
  const int koff0 = krow * 128 + (((2 * kseg)     ^ (krow & 15)) << 3);
  const int koff1 = krow * 128 + (((2 * kseg + 1) ^ (krow & 15)) << 3);
  // V role: 256 thr, each 2 consecutive token rows x 8 floats.
  // Bit split (conflict fix): mpr = b0-2 | b4<<3 ; token-pair = b3 | b5-7<<1.
  const int vt  = tid & 255;
  const int mpr = (vt & 7) | (((vt >> 4) & 1) << 3);   // d-chunk 0..15
  const int tv  = (((vt >> 3) & 1) | ((vt >> 5) << 1)) * 2;  // 0,2,..,30
  const float* vsrc = V + ((size_t)(b * S_ + tv) * KVH_ + kvh) * D_ + mpr * 8;
  const int vbase = mpr * 256 + (tv & 7);  // (dv0+e)*32 = mpr*256 + e*32
  const int vch   = (tv >> 3) ^ ((mpr >> 1) & 3);

  const int t_lo = (i0 >= WIN_) ? ((i0 - (WIN_ - 1)) >> 5) : 0;
  const int t_hi = i0 >> 5;

  float4 r0, r1, r2, r3;
  auto loadStage = [&](int j0v) {
    if (isK) {
      const float* p = ksrc + (size_t)j0v * KVD_;
      r0 = *(const float4*)(p);      r1 = *(const float4*)(p + 4);
      r2 = *(const float4*)(p + 8);  r3 = *(const float4*)(p + 12);
    } else {
      const float* p = vsrc + (size_t)j0v * KVD_;
      r0 = *(const float4*)(p);            r1 = *(const float4*)(p + 4);
      r2 = *(const float4*)(p + KVD_);     r3 = *(const float4*)(p + KVD_ + 4);
    }
  };
  auto writeStage = [&](int bi) {
    if (isK) {
      bf16x8 lo = { (bf16_t)r0.x, (bf16_t)r0.y, (bf16_t)r0.z, (bf16_t)r0.w,
                    (bf16_t)r1.x, (bf16_t)r1.y, (bf16_t)r1.z, (bf16_t)r1.w };
      bf16x8 hi = { (bf16_t)r2.x, (bf16_t)r2.y, (bf16_t)r2.z, (bf16_t)r2.w,
                    (bf16_t)r3.x, (bf16_t)r3.y, (bf16_t)r3.z, (bf16_t)r3.w };
      *(bf16x8*)&KsB[bi][koff0] = lo;
      *(bf16x8*)&KsB[bi][koff1] = hi;
    } else {
      const float av[8] = { r0.x, r0.y, r0.z, r0.w, r1.x, r1.y, r1.z, r1.w };
      const float bv[8] = { r2.x, r2.y, r2.z, r2.w, r3.x, r3.y, r3.z, r3.w };
      #pragma unroll
      for (int e = 0; e < 8; ++e) {
        bf16x2 pr = { (bf16_t)av[e], (bf16_t)bv[e] };
        *(bf16x2*)&VtB[bi][vbase + e * 32 + ((vch ^ (e >> 1)) << 3)] = pr;
      }
    }
  };

  // prologue: stage tile t_lo into buffer 0
  loadStage(t_lo * 32);
  writeStage(0);
  __syncthreads();
  int buf = 0;

  for (int tb = t_lo; tb <= t_hi; ++tb) {
    const int j0  = tb * 32;
    const bool pre = (tb < t_hi);
    if (pre) loadStage(j0 + 32);   // issue-early; latency hides under compute

    if (!(j0 > iw + 15 || j0 + 31 < iw - (WIN_ - 1))) {
      const bool full = (j0 + 31 <= iw) && (iw + 15 - j0 < WIN_);
      const int pw = w * (16 * 32);

      // ---- S^T = K·Q^T, fused softcap -> p (fixed max) -> P to LDS ----
      #pragma unroll
      for (int t4 = 0; t4 < 2; ++t4) {
        f32x4 acc = (f32x4){0.f, 0.f, 0.f, 0.f};
        const int row = 16 * t4 + m16;
        __builtin_amdgcn_s_setprio(1);
        #pragma unroll
        for (int s = 0; s < 4; ++s) {
          bf16x8 a = *(const bf16x8*)&KsB[buf][row * 128 + (((quad + 4 * s) ^ m16) << 3)];
          acc = __builtin_amdgcn_mfma_f32_16x16x32_bf16(a, qf[s], acc, 0, 0, 0);
        }
        __builtin_amdgcn_s_setprio(0);
        bf16x4 pk;
        #pragma unroll
        for (int r = 0; r < 4; ++r) {
          float ez = EXP2F_(acc[r] * C1_);
          float p  = EXP2F_(NK22_ * __builtin_amdgcn_rcpf(ez + 1.f));
          if (!full) {
            const int j = j0 + t4 * 16 + 4 * quad + r;
            p = ((j <= i) && (i - j < WIN_)) ? p : 0.f;
          }
          lacc[r] += p;
          pk[r] = (bf16_t)p;
        }
        const int ch = (2 * t4 + (quad >> 1)) ^ sw16;
        *(bf16x4*)&PsB[pw + m16 * 32 + ch * 8 + (quad & 1) * 4] = pk;
      }
      bf16x8 pa = *(const bf16x8*)&PsB[pw + m16 * 32 + ((quad ^ sw16) << 3)];

      // ---- O += P·V  (V^T read: chunk = quad ^ sw16 ^ (c&3)) ----
      __builtin_amdgcn_s_setprio(1);
      #pragma unroll
      for (int c = 0; c < 8; ++c) {
        const int vrow = 16 * c + m16;
        bf16x8 v = *(const bf16x8*)&VtB[buf][vrow * 32 + (((quad ^ sw16) ^ (c & 3)) << 3)];
        O[c] = __builtin_amdgcn_mfma_f32_16x16x32_bf16(pa, v, O[c], 0, 0, 0);
      }
      __builtin_amdgcn_s_setprio(0);
    }

    if (pre) writeStage(buf ^ 1);  // write-late: cvt + swizzled LDS stores
    __syncthreads();
    buf ^= 1;
  }

  // ---- epilogue: one deferred row-sum reduce, then scale + store ----
  float l_run = lacc[0] + lacc[1] + lacc[2] + lacc[3];
  l_run += __shfl_xor(l_run, 16);
  l_run += __shfl_xor(l_run, 32);

  float* ob = Out + ((size_t)(b * S_ + iw) * H_ + h) * D_;
  #pragma unroll
  for (int r = 0; r < 4; ++r) {
    const int rr = 4 * quad + r;
    const float lr = __shfl(l_run, rr);
    const float linv = __builtin_amdgcn_rcpf(lr);
    float* po = ob + (size_t)rr * (H_ * D_);
    #pragma unroll
    for (int c = 0; c < 8; ++c) po[c * 16 + m16] = O[c][r] * linv;
  }
}

extern "C" void kernel_launch(void* const* d_in, const int* in_sizes, int n_in,
                              void* d_out, int out_size, void* d_ws, size_t ws_size,
                              hipStream_t stream) {
  const float* q = (const float*)d_in[0];
  const float* k = (const float*)d_in[1];
  const float* v = (const float*)d_in[2];
  float* out = (float*)d_out;
  // Single fused kernel: no prepass, no workspace, no input mutation.
  attn_fwd<<<dim3(S_ / 32, KVH_, B_), 512, 0, stream>>>(q, k, v, out);
}